// Round 10
// baseline (315.005 us; speedup 1.0000x reference)
//
#include <hip/hip_runtime.h>

// KAN-CNN via MFMA: out[b,f,h,w] = sum_{dy,dx,c} R_{f,dy,dx,c}( xpad[b,c,h+dy-1,w+dx-1] )
// R(x) = P5(x)/(1+|x*Q(x)|).
//
// R14: R13 showed duration decoupled from VALU-issue count (busy 190k->173k,
// dur flat at ~105us) with Occupancy 38% (~3 waves/SIMD): latency-stall
// bound. Fix the register state, not the arithmetic: 16x16x32 MFMA
// (D = 4 regs, C/D map m89/m91: col=lane&15, row=(lane>>4)*4+reg) with one
// (16f,16px) tile per wave looping ALL 288 taps. acc=4 regs, live set ~55
// -> __launch_bounds__(256,8) = 8 waves/SIMD full residency; LDS reduction
// and __syncthreads eliminated. Grid 2048 x 4 waves = 8192 waves = exactly
// 8/SIMD, no tail. K 16..31 zeroed via a dedicated zero slot that B-lane
// groups 2,3 point at (per-lane base + masked advance; A there is ignored
// since B=0). A/B built with the SAME (lanegroup,slot) placement -> HW
// k-permutation cancels (R8-validated argument). Numerics identical to R13
// (hi/lo split dot + paired-tap epilogue, 1 rcp per elem-pair).

typedef int   iv4 __attribute__((ext_vector_type(4)));
typedef short s8v __attribute__((ext_vector_type(8)));
typedef float f4v __attribute__((ext_vector_type(4)));

#define Bb 8
#define Cc 32
#define Hh 64
#define Ww 64
#define Ff 64
#define PW 66
#define PPLANE (PW * PW)             // 4356
#define NELEM  (Bb * Cc * PPLANE)    // 1,115,136 elements
#define NTAP   288
#define NTP    144                   // tap pairs
#define PWBLK  (NELEM / 256)         // 4356 blocks for powers part
#define ACTN   (NTP * 4 * 4 * 64)    // 147,456 entries (2.36 MB)
#define ABLK   (ACTN / 256)          // 576 blocks for A part
#define ZIDX   (2 * NELEM)           // zero slot (iv4 index into pw space)

static __device__ __forceinline__ unsigned short f2bf(float f) {
    unsigned u = __builtin_bit_cast(unsigned, f);
    u += 0x7fffu + ((u >> 16) & 1u);           // RNE
    return (unsigned short)(u >> 16);
}
static __device__ __forceinline__ float bf2f(unsigned short h) {
    unsigned u = ((unsigned)h) << 16;
    return __builtin_bit_cast(float, u);
}
static __device__ __forceinline__ int pack2(unsigned short a, unsigned short b) {
    return (int)((unsigned)a | ((unsigned)b << 16));
}
static __device__ __forceinline__ iv4 ld16(const char* p) {
    return *(const iv4* __restrict__)p;
}

// Merged prep. Blocks [0,PWBLK): powers planes (r0 at pw[e], r1 at
// pw[NELEM+e]) + zero slot at pw[ZIDX]. Blocks [PWBLK, PWBLK+ABLK):
// A fragments, layout act[((tp*4+fg)*4+j)*64+l], j: 0=num t0,1=den t0,
// 2=num t1,3=den t1 (t0=2tp, t1=2tp+1); lane l: f=fg*16+(l&15),
// row-half=(l>>4)&1 (lanes 32-63 replicate; their k's see B=0).
__global__ __launch_bounds__(256) void prep_kernel(
    const float* __restrict__ x,
    const float* __restrict__ ncf, const float* __restrict__ dcf,
    iv4* __restrict__ pw)
{
    if ((int)blockIdx.x < PWBLK) {
        int idx = (int)blockIdx.x * 256 + (int)threadIdx.x;
        if (idx == 0) { iv4 z = {0, 0, 0, 0}; pw[ZIDX] = z; }
        int wp = idx % PW;
        int r1 = idx / PW;
        int hp = r1 % PW;
        int pl = r1 / PW;                                 // b*32+c
        float v = 0.0f;
        if (hp >= 1 && hp <= Hh && wp >= 1 && wp <= Ww)
            v = x[((size_t)pl * Hh + (hp - 1)) * Ww + (wp - 1)];
        float p2 = v * v, p3 = p2 * v, p4 = p2 * p2, p5 = p4 * v;
        float pv[6] = {1.0f, v, p2, p3, p4, p5};
        unsigned short hi[6], lo[6];
#pragma unroll
        for (int e = 0; e < 6; ++e) {
            hi[e] = f2bf(pv[e]);
            lo[e] = f2bf(pv[e] - bf2f(hi[e]));
        }
        iv4 r0, r1v;
        r0.x  = pack2(hi[0], hi[1]); r0.y  = pack2(hi[2], hi[3]);
        r0.z  = pack2(hi[4], hi[5]); r0.w  = pack2(lo[1], lo[2]);
        r1v.x = pack2(lo[3], lo[4]); r1v.y = pack2(lo[5], hi[1]);
        r1v.z = pack2(hi[2], hi[3]); r1v.w = pack2(hi[4], hi[5]);
        pw[idx]         = r0;
        pw[NELEM + idx] = r1v;
    } else {
        int idx = ((int)blockIdx.x - PWBLK) * 256 + (int)threadIdx.x;
        int l  = idx & 63;
        int j  = (idx >> 6) & 3;
        int fg = (idx >> 8) & 3;
        int tp = idx >> 10;
        int t  = 2 * tp + (j >> 1);
        int nd = j & 1;
        int f  = fg * 16 + (l & 15);
        int half = (l >> 4) & 1;
        float cv[6];
        if (nd == 0) {
            const float* s = ncf + ((size_t)f * NTAP + t) * 6;
            cv[0] = s[0]; cv[1] = s[1]; cv[2] = s[2];
            cv[3] = s[3]; cv[4] = s[4]; cv[5] = s[5];
        } else {
            const float* s = dcf + ((size_t)f * NTAP + t) * 4;
            cv[0] = 0.0f; cv[1] = s[0]; cv[2] = s[1];
            cv[3] = s[2]; cv[4] = s[3]; cv[5] = 0.0f;
        }
        unsigned short chi[6], clo[6];
#pragma unroll
        for (int e = 0; e < 6; ++e) {
            chi[e] = f2bf(cv[e]);
            clo[e] = f2bf(cv[e] - bf2f(chi[e]));
        }
        iv4 o;
        if (half == 0) {  // pairs with B r0 = [phi0..phi5, plo1, plo2]
            o.x = pack2(chi[0], chi[1]); o.y = pack2(chi[2], chi[3]);
            o.z = pack2(chi[4], chi[5]); o.w = pack2(chi[1], chi[2]);
        } else {          // pairs with B r1 = [plo3, plo4, plo5, phi1..phi5]
            o.x = pack2(chi[3], chi[4]); o.y = pack2(chi[5], clo[1]);
            o.z = pack2(clo[2], clo[3]); o.w = pack2(clo[4], clo[5]);
        }
        iv4* act = pw + (ZIDX + 1);
        act[idx] = o;
    }
}

// 2048 blocks x 256 (4 waves). Block = (b, h, w-quarter of 16 px); wave fg
// owns filters [16fg, 16fg+16) and loops all 288 taps as 144 pairs.
// No LDS, no syncthreads. 8 waves/SIMD full residency.
__global__ __launch_bounds__(256, 8) void kan_mfma_kernel(
    const iv4* __restrict__ pw, float* __restrict__ out)
{
    const int tid = threadIdx.x;
    const int l  = tid & 63, fg = tid >> 6;
    const int px = l & 15, g = l >> 4;
    const int gb = (int)blockIdx.x;
    const int wq = gb & 3, h = (gb >> 2) & 63, bb = gb >> 8;
    const int w0 = wq << 4;

    const char* __restrict__ pwc  = (const char*)pw;
    const char* __restrict__ actc = (const char*)(pw + (ZIDX + 1));

    // per-lane B addressing: g=0 -> r0 plane, g=1 -> r1 plane, g>=2 -> zero slot
    const unsigned laneBaseB =
        (g == 0) ? (unsigned)(px * 16)
      : (g == 1) ? (unsigned)((NELEM + px) * 16)
      :            (unsigned)(ZIDX * 16);
    const unsigned maskE = (g < 2) ? 0xFFFFFFFFu : 0u;
    const unsigned dB    = ((unsigned)(PPLANE * 16)) & maskE;   // +1 channel

    f4v acc = {0.0f, 0.0f, 0.0f, 0.0f};
    f4v zf  = {0.0f, 0.0f, 0.0f, 0.0f};

    unsigned offA = (unsigned)(fg * 4096 + l * 16);   // advances 16384/pair

#pragma unroll 1
    for (int k2 = 0; k2 < 9; ++k2) {
        const int dy = k2 / 3, dx = k2 - 3 * dy;
        const int elemw = ((bb * Cc) * PW + (h + dy)) * PW + (w0 + dx);
        unsigned offB = laneBaseB + (((unsigned)(elemw * 16)) & maskE);

#pragma unroll 1
        for (int pp = 0; pp < 16; ++pp) {
            iv4 B0 = ld16(pwc + offB);
            unsigned offB1 = offB + dB;
            iv4 B1 = ld16(pwc + offB1);
            offB = offB1 + dB;

            iv4 An0 = ld16(actc + offA);
            iv4 Ad0 = ld16(actc + offA + 1024);
            iv4 An1 = ld16(actc + offA + 2048);
            iv4 Ad1 = ld16(actc + offA + 3072);
            offA += 16384;

            s8v b0 = __builtin_bit_cast(s8v, B0);
            s8v b1 = __builtin_bit_cast(s8v, B1);

            f4v Dn0 = __builtin_amdgcn_mfma_f32_16x16x32_bf16(
                __builtin_bit_cast(s8v, An0), b0, zf, 0, 0, 0);
            f4v Dd0 = __builtin_amdgcn_mfma_f32_16x16x32_bf16(
                __builtin_bit_cast(s8v, Ad0), b0, zf, 0, 0, 0);
            f4v Dn1 = __builtin_amdgcn_mfma_f32_16x16x32_bf16(
                __builtin_bit_cast(s8v, An1), b1, zf, 0, 0, 0);
            f4v Dd1 = __builtin_amdgcn_mfma_f32_16x16x32_bf16(
                __builtin_bit_cast(s8v, Ad1), b1, zf, 0, 0, 0);

            // paired epilogue: ONE rcp per element-pair
#pragma unroll
            for (int r = 0; r < 4; ++r) {
                float da = 1.0f + __builtin_fabsf(Dd0[r]);
                float db = 1.0f + __builtin_fabsf(Dd1[r]);
                float nn = __builtin_fmaf(Dn0[r], db, Dn1[r] * da);
                float rc = __builtin_amdgcn_rcpf(da * db);
                acc[r] = __builtin_fmaf(nn, rc, acc[r]);
            }
        }
    }

    // C/D map (m89/m91): col = lane&15 = px, row = (lane>>4)*4 + r = f%16
    float* o = out + (((size_t)(bb * Ff + fg * 16 + g * 4) * Hh + h) * Ww) + w0 + px;
#pragma unroll
    for (int r = 0; r < 4; ++r)
        o[(size_t)r * Hh * Ww] = acc[r];
}

extern "C" void kernel_launch(void* const* d_in, const int* in_sizes, int n_in,
                              void* d_out, int out_size, void* d_ws, size_t ws_size,
                              hipStream_t stream) {
    const float* x   = (const float*)d_in[0];
    const float* ncf = (const float*)d_in[1];
    const float* dcf = (const float*)d_in[2];
    float* out = (float*)d_out;

    iv4* pw = (iv4*)d_ws;   // planes 35.7MB + zero slot + act 2.36MB = 38.1MB

    prep_kernel<<<PWBLK + ABLK, 256, 0, stream>>>(x, ncf, dcf, pw);
    kan_mfma_kernel<<<2048, 256, 0, stream>>>(pw, out);
}